// Round 1
// baseline (1435.873 us; speedup 1.0000x reference)
//
#include <hip/hip_runtime.h>

// SAGE_38113539785173 — 3-layer GraphSAGE inference on MI355X (gfx950).
// Round 10: src-chunked gather for per-XCD L2 locality.
//   Round-9 profile: slowest k_sage (all top-5 rows are the same dispatch
//   position mod 26) = 114us, FETCH 185MB @ ~1.8TB/s on the L2-miss path,
//   VALUBusy 18%, MfmaUtil 0.5% -> pure L2-miss-BW wall on the random gather
//   (12.8MB bf16 table vs 4MB per-XCD L2; reuse = E/(8N) = 2x uncaptured).
//   - CSR rows are now sub-ordered by src-chunk (8 chunks of N/8 rows, 2MB
//     bf16 each): k_fine ranks by key=(dst&511)*8+(src>>sh) and emits
//     per-node byte sub-offsets rsc8[N*8] (deg>255 -> fallback: all in c=7).
//   - k_sage gathers chunk-OUTER across its 16 nodes, accumulating partial
//     sums in LDS fp32 sAcc[wave][16][64] (+16KB -> 52.7KB, 3 blocks/CU,
//     grid 768). All resident waves sweep chunks in order -> L2 working set
//     ~2-4MB instead of 12.8MB. Predicted FETCH 185 -> ~120-140MB.
//   BN fusion (stats epilogue + BNIN prologue), MFMA dual-matmul, CSR build
//   (hist->btot->hoff->scat->fine, no global atomics) otherwise unchanged.

constexpr float BN_EPS = 1e-5f;

typedef __attribute__((ext_vector_type(8))) short bf16x8;
typedef __attribute__((ext_vector_type(4))) float f32x4;

// ---- bf16 helpers -----------------------------------------------------------
__device__ __forceinline__ float bf2f(unsigned short u) {
  union { unsigned int i; float f; } c;
  c.i = (unsigned int)u << 16;
  return c.f;
}
__device__ __forceinline__ unsigned short f2bf(float v) {
  union { float f; unsigned int i; } c;
  c.f = v;
  unsigned int r = c.i + 0x7fffu + ((c.i >> 16) & 1u);  // round-nearest-even
  return (unsigned short)(r >> 16);
}

__device__ __forceinline__ void st_f(float* p, size_t i, float v) { p[i] = v; }
__device__ __forceinline__ void st_f(unsigned short* p, size_t i, float v) {
  p[i] = f2bf(v);
}

// row loaders: 16 lanes x (16B fp32 | 8B bf16) per 64-channel row
__device__ __forceinline__ float4 ld_row(const float* p, int row, int li) {
  return ((const float4*)p)[(size_t)row * 16 + li];
}
__device__ __forceinline__ float4 ld_row(const unsigned short* p, int row, int li) {
  ushort4 u = ((const ushort4*)p)[(size_t)row * 16 + li];
  float4 f;
  f.x = bf2f(u.x); f.y = bf2f(u.y); f.z = bf2f(u.z); f.w = bf2f(u.w);
  return f;
}

// ------------------------------------------------- edge dtype probe (1 block)
__global__ __launch_bounds__(256) void k_probe(const int* __restrict__ w, int E,
                                               int* __restrict__ dflag) {
  __shared__ int any;
  if (threadIdx.x == 0) any = 0;
  __syncthreads();
  const int twoE = 2 * E;
  int local = 0;
  for (int i = 0; i < 8; ++i) {
    long long idx = (long long)(threadIdx.x * 8 + i) * twoE / 2048;
    int wi = (int)(idx | 1);
    if (wi < twoE && w[wi] != 0) local = 1;
  }
  if (local) atomicOr(&any, 1);
  __syncthreads();
  if (threadIdx.x == 0) *dflag = any;  // 1 => int32 edges, 0 => int64 edges
}

__device__ __forceinline__ void load_edge(const void* ei, int e, int E, int is32,
                                          int& src, int& dst) {
  if (is32) {
    const int* p = (const int*)ei;
    src = p[e];
    dst = p[E + e];
  } else {
    const long long* p = (const long long*)ei;
    src = (int)p[e];
    dst = (int)p[(long long)E + e];
  }
}

// --------------------------------- CSR phase 1: per-block bucket histograms
__global__ __launch_bounds__(256) void k_hist(const void* __restrict__ ei, int E,
                                              int N, const int* __restrict__ dflag,
                                              int NB, int chunk,
                                              int* __restrict__ hist) {
  __shared__ int h[256];
  h[threadIdx.x] = 0;
  __syncthreads();
  const int is32 = *dflag;
  int lo = blockIdx.x * chunk;
  int hi = lo + chunk;
  if (hi > E) hi = E;
  for (int e = lo + threadIdx.x; e < hi; e += 256) {
    int src, dst;
    load_edge(ei, e, E, is32, src, dst);
    if ((unsigned)src < (unsigned)N && (unsigned)dst < (unsigned)N)
      atomicAdd(&h[dst >> 9], 1);
  }
  __syncthreads();
  if (threadIdx.x < NB) hist[blockIdx.x * NB + threadIdx.x] = h[threadIdx.x];
}

// ------------------- CSR phase 2a: bucket totals + base offsets (+zero stats)
__global__ __launch_bounds__(256) void k_btot(const int* __restrict__ hist,
                                              int NBLK, int NB,
                                              int* __restrict__ bucket_base,
                                              float* __restrict__ stats) {
  stats[threadIdx.x] = 0.0f;  // zero both layers' raw-sum slots (256 floats)
  __shared__ int part[256];
  int t = threadIdx.x;
  int s = 0;
  if (t < NB)
    for (int b = 0; b < NBLK; ++b) s += hist[b * NB + t];
  part[t] = s;
  __syncthreads();
  for (int off = 1; off < 256; off <<= 1) {
    int u = (t >= off) ? part[t - off] : 0;
    __syncthreads();
    part[t] += u;
    __syncthreads();
  }
  if (t < NB) bucket_base[t] = part[t] - s;
  if (t == NB - 1) bucket_base[NB] = part[t];
}

// --------------------------------- CSR phase 2b: per-(block,bucket) offsets
__global__ __launch_bounds__(64) void k_hoff(const int* __restrict__ hist,
                                             int NBLK, int NB,
                                             const int* __restrict__ bucket_base,
                                             int* __restrict__ offs) {
  int b = blockIdx.x;
  int lane = threadIdx.x;
  int carry = bucket_base[b];
  for (int c = 0; c < NBLK; c += 64) {
    int blk = c + lane;
    int v = (blk < NBLK) ? hist[blk * NB + b] : 0;
    int incl = v;
    for (int off = 1; off < 64; off <<= 1) {
      int u = __shfl_up(incl, off);
      if (lane >= off) incl += u;
    }
    if (blk < NBLK) offs[blk * NB + b] = carry + incl - v;
    carry += __shfl(incl, 63);
  }
}

// --------------------------------- CSR phase 3: bucket-grouped scatter
__global__ __launch_bounds__(256) void k_scat(const void* __restrict__ ei, int E,
                                              int N, const int* __restrict__ dflag,
                                              int NB, int chunk,
                                              const int* __restrict__ offs,
                                              unsigned* __restrict__ csr) {
  __shared__ int cur[256];
  if (threadIdx.x < NB) cur[threadIdx.x] = offs[blockIdx.x * NB + threadIdx.x];
  __syncthreads();
  const int is32 = *dflag;
  int lo = blockIdx.x * chunk;
  int hi = lo + chunk;
  if (hi > E) hi = E;
  for (int e = lo + threadIdx.x; e < hi; e += 256) {
    int src, dst;
    load_edge(ei, e, E, is32, src, dst);
    if ((unsigned)src < (unsigned)N && (unsigned)dst < (unsigned)N) {
      int p = atomicAdd(&cur[dst >> 9], 1);
      csr[p] = ((unsigned)src << 9) | (unsigned)(dst & 511);
    }
  }
}

// --------- CSR phase 4: per-bucket permutation, ordered by (dst, src-chunk)
// key = (dst&511)*8 + (src>>sh); counters packed 2x16-bit to fit 64KB LDS.
// Emits per-node chunk sub-offsets rsc8[node*8+c] (bytes; deg>255 -> all 0,
// meaning "all edges live in chunk 7" — k_sage handles that correctly).
__global__ __launch_bounds__(256) void k_fine(unsigned* __restrict__ csr,
                                              const int* __restrict__ bucket_base,
                                              int N, int sh,
                                              int* __restrict__ row_start,
                                              unsigned char* __restrict__ rsc8) {
  constexpr int CAP = 12160;
  __shared__ unsigned lrec[CAP];
  __shared__ int lcntP[2048];  // 4096 counts packed 2x16
  __shared__ int curP[2048];   // 4096 cursors packed 2x16 (abs offs < 12160)
  __shared__ int wtot[4];
  const int b = blockIdx.x;
  const int lo = bucket_base[b];
  int cnt = bucket_base[b + 1] - lo;
  if (cnt > CAP) cnt = CAP;
  const int t = threadIdx.x;
  for (int i = t; i < 2048; i += 256) lcntP[i] = 0;
  __syncthreads();
  for (int i = t; i < cnt; i += 256) {
    unsigned r = csr[lo + i];
    lrec[i] = r;
    int key = (int)((r & 511u) << 3) | (int)((r >> 9) >> sh);
    atomicAdd(&lcntP[key >> 1], 1 << ((key & 1) * 16));
  }
  __syncthreads();
  // thread t owns keys [16t,16t+16) = dsts {2t,2t+1} x 8 chunks
  int v[16], s = 0;
#pragma unroll
  for (int i = 0; i < 16; ++i) {
    int wd = lcntP[t * 8 + (i >> 1)];
    v[i] = (wd >> ((i & 1) * 16)) & 0xffff;
    s += v[i];
  }
  int incl = s;
  const int lane = t & 63;
  for (int off = 1; off < 64; off <<= 1) {
    int u = __shfl_up(incl, off);
    if (lane >= off) incl += u;
  }
  const int wv = t >> 6;
  if (lane == 63) wtot[wv] = incl;
  __syncthreads();
  int woff = 0;
  for (int i = 0; i < wv; ++i) woff += wtot[i];
  const int excl = woff + incl - s;
  int pre[17];
  pre[0] = 0;
#pragma unroll
  for (int i = 0; i < 16; ++i) pre[i + 1] = pre[i] + v[i];
#pragma unroll
  for (int j = 0; j < 8; ++j) {
    int loh = excl + pre[2 * j];
    int hih = excl + pre[2 * j + 1];
    curP[t * 8 + j] = loh | (hih << 16);
  }
  int gi = b * 512 + 2 * t;
  if (gi <= N) row_start[gi] = lo + excl;
  if (gi + 1 <= N) row_start[gi + 1] = lo + excl + pre[8];
  if (rsc8) {
    if (gi < N) {
      unsigned long long wq = 0;
      if (pre[8] <= 255) {
#pragma unroll
        for (int c = 0; c < 8; ++c)
          wq |= (unsigned long long)(unsigned)pre[c] << (8 * c);
      }
      *(unsigned long long*)(rsc8 + (size_t)gi * 8) = wq;
    }
    if (gi + 1 < N) {
      unsigned long long wq = 0;
      int d1 = pre[16] - pre[8];
      if (d1 <= 255) {
#pragma unroll
        for (int c = 0; c < 8; ++c)
          wq |= (unsigned long long)(unsigned)(pre[8 + c] - pre[8]) << (8 * c);
      }
      *(unsigned long long*)(rsc8 + (size_t)(gi + 1) * 8) = wq;
    }
  }
  __syncthreads();
  for (int i = t; i < cnt; i += 256) {
    unsigned r = lrec[i];
    int key = (int)((r & 511u) << 3) | (int)((r >> 9) >> sh);
    int sft = (key & 1) * 16;
    int old = atomicAdd(&curP[key >> 1], 1 << sft);
    int p = (old >> sft) & 0xffff;
    csr[lo + p] = r >> 9;
  }
}

// --------------- fused gather-mean + MFMA dual matmul + BN-in + BN-out stats
// Gather is src-chunk-OUTER: partial sums accumulate in LDS fp32 sAcc so the
// per-XCD L2 working set is one ~2MB chunk instead of the whole 12.8MB table.
template <int COUT, bool BNIN, bool BNOUT, typename TI, typename TO>
__global__ __launch_bounds__(256, 3) void k_sage(
    const TI* __restrict__ hin, const int* __restrict__ row_start,
    const int* __restrict__ csr, const unsigned char* __restrict__ rsc8,
    const float* __restrict__ Wl, const float* __restrict__ Wr,
    const float* __restrict__ bias, const float* __restrict__ statsIn,
    const float* __restrict__ gIn, const float* __restrict__ beIn,
    float* __restrict__ statsOut, TO* __restrict__ out, int n) {
  constexpr int NT = (COUT + 15) / 16;
  __shared__ short sWf[NT][4][64][8];  // B-fragments: [nt][kt][lane][j]
  __shared__ short sA[4][16][136];     // [wave][node][k: mean 0..63|self 64..127]
  __shared__ float sAcc[4][16][64];    // chunked-gather fp32 partial sums
  __shared__ float sBN[2][64];         // BNIN: per-channel scale / shift
  __shared__ float sRed[2][4][64];     // BNOUT: per-wave channel partials

  for (int t = threadIdx.x; t < NT * 4 * 64; t += 256) {
    int lane = t & 63;
    int kt = (t >> 6) & 3;
    int nt = t >> 8;
    int kbase = kt * 32 + (lane >> 4) * 8;
    int col = nt * 16 + (lane & 15);
#pragma unroll
    for (int j = 0; j < 8; ++j) {
      int k = kbase + j;
      float wv = 0.0f;
      if (col < COUT) wv = (k < 64) ? Wl[k * COUT + col] : Wr[(k - 64) * COUT + col];
      sWf[nt][kt][lane][j] = (short)f2bf(wv);
    }
  }
  if (BNIN && threadIdx.x < 64) {
    int c = threadIdx.x;
    float inv = 1.0f / (float)n;
    float mu = statsIn[c] * inv;
    float var = statsIn[64 + c] * inv - mu * mu;
    var = var < 0.f ? 0.f : var;
    float sc = gIn[c] * rsqrtf(var + BN_EPS);
    sBN[0][c] = sc;
    sBN[1][c] = beIn[c] - mu * sc;
  }
  __syncthreads();

  const int wave = threadIdx.x >> 6;
  const int lane = threadIdx.x & 63;
  const int g = lane >> 4;
  const int li = lane & 15;
  const int quad = lane >> 4;
  const int col16 = lane & 15;

  // per-lane BN-in coefficients for channels li*4..li*4+3
  float4 bsc = make_float4(1.f, 1.f, 1.f, 1.f);
  float4 bsh = make_float4(0.f, 0.f, 0.f, 0.f);
  if (BNIN) {
    bsc = *(const float4*)&sBN[0][li * 4];
    bsh = *(const float4*)&sBN[1][li * 4];
  }
  auto xf = [&](float4 v) -> float4 {
    if (!BNIN) return v;
    float4 r;
    r.x = fmaxf(v.x * bsc.x + bsh.x, 0.f);
    r.y = fmaxf(v.y * bsc.y + bsh.y, 0.f);
    r.z = fmaxf(v.z * bsc.z + bsh.z, 0.f);
    r.w = fmaxf(v.w * bsc.w + bsh.w, 0.f);
    return r;
  };

  float bias_r[NT];
#pragma unroll
  for (int nt = 0; nt < NT; ++nt) {
    int c = nt * 16 + col16;
    bias_r[nt] = (c < COUT) ? bias[c] : 0.0f;
  }

  float statS[NT], statQ[NT];
#pragma unroll
  for (int nt = 0; nt < NT; ++nt) { statS[nt] = 0.f; statQ[nt] = 0.f; }

  const int wgl = blockIdx.x * 4 + wave;
  const int nstride = gridDim.x * 64;

  for (int base = wgl * 16; base < n; base += nstride) {
    // zero my wave's 16x64 fp32 accumulators (wave-local, no block sync)
    {
      float* pz = (float*)sAcc[wave];
#pragma unroll
      for (int i = 0; i < 16; ++i) pz[i * 64 + lane] = 0.f;
    }
    __builtin_amdgcn_wave_barrier();

#pragma unroll 1
    for (int c = 0; c < 8; ++c) {
#pragma unroll 1
      for (int nb = 0; nb < 16; ++nb) {
        int node = base + nb;
        if (node >= n) break;
        int rs = row_start[node];
        int deg = row_start[node + 1] - rs;
        int b0 = 0, b1 = deg;
        if (rsc8) {
          const unsigned char* rr = rsc8 + (size_t)node * 8;
          b0 = c ? (int)rr[c] : 0;
          b1 = (c == 7) ? deg : (int)rr[c + 1];
        } else if (c != 7) {
          b1 = 0;  // ws-fallback: process everything in the c==7 pass
        }
        if (b0 >= b1) continue;
        float4 acc = make_float4(0.f, 0.f, 0.f, 0.f);
        int e = rs + b0 + g;
        const int re = rs + b1;
        for (; e + 12 < re; e += 16) {  // 4 rows in flight per group
          int r0 = csr[e], r1 = csr[e + 4], r2 = csr[e + 8], r3 = csr[e + 12];
          float4 f0 = xf(ld_row(hin, r0, li));
          float4 f1 = xf(ld_row(hin, r1, li));
          float4 f2 = xf(ld_row(hin, r2, li));
          float4 f3 = xf(ld_row(hin, r3, li));
          acc.x += (f0.x + f1.x) + (f2.x + f3.x);
          acc.y += (f0.y + f1.y) + (f2.y + f3.y);
          acc.z += (f0.z + f1.z) + (f2.z + f3.z);
          acc.w += (f0.w + f1.w) + (f2.w + f3.w);
        }
        for (; e < re; e += 4) {
          float4 f0 = xf(ld_row(hin, csr[e], li));
          acc.x += f0.x; acc.y += f0.y; acc.z += f0.z; acc.w += f0.w;
        }
        acc.x += __shfl_xor(acc.x, 16); acc.x += __shfl_xor(acc.x, 32);
        acc.y += __shfl_xor(acc.y, 16); acc.y += __shfl_xor(acc.y, 32);
        acc.z += __shfl_xor(acc.z, 16); acc.z += __shfl_xor(acc.z, 32);
        acc.w += __shfl_xor(acc.w, 16); acc.w += __shfl_xor(acc.w, 32);
        if (g == 0) {
          float4* pa = (float4*)&sAcc[wave][nb][li * 4];
          float4 o = *pa;
          o.x += acc.x; o.y += acc.y; o.z += acc.z; o.w += acc.w;
          *pa = o;
        }
      }
    }
    __builtin_amdgcn_wave_barrier();

    // finalize: mean + self -> bf16 A-fragments
#pragma unroll 1
    for (int nb = 0; nb < 16; ++nb) {
      int node = base + nb;
      if (node >= n) break;
      int deg = row_start[node + 1] - row_start[node];
      float invd = 1.0f / (float)(deg > 0 ? deg : 1);
      float4 m = *(const float4*)&sAcc[wave][nb][li * 4];
      float4 self = xf(ld_row(hin, node, li));
      ushort4 mv, sv;
      mv.x = f2bf(m.x * invd); mv.y = f2bf(m.y * invd);
      mv.z = f2bf(m.z * invd); mv.w = f2bf(m.w * invd);
      sv.x = f2bf(self.x); sv.y = f2bf(self.y);
      sv.z = f2bf(self.z); sv.w = f2bf(self.w);
      *(ushort4*)&sA[wave][nb][li * 4] = mv;
      *(ushort4*)&sA[wave][nb][64 + li * 4] = sv;
    }
    __builtin_amdgcn_wave_barrier();

    f32x4 acc[NT];
#pragma unroll
    for (int nt = 0; nt < NT; ++nt) acc[nt] = (f32x4){0.f, 0.f, 0.f, 0.f};
#pragma unroll
    for (int kt = 0; kt < 4; ++kt) {
      bf16x8 a = *(const bf16x8*)&sA[wave][lane & 15][kt * 32 + (lane >> 4) * 8];
#pragma unroll
      for (int nt = 0; nt < NT; ++nt) {
        bf16x8 b = *(const bf16x8*)&sWf[nt][kt][lane][0];
        acc[nt] = __builtin_amdgcn_mfma_f32_16x16x32_bf16(a, b, acc[nt], 0, 0, 0);
      }
    }
    __builtin_amdgcn_wave_barrier();

#pragma unroll
    for (int nt = 0; nt < NT; ++nt) {
      int c = nt * 16 + col16;
      if (c < COUT) {
#pragma unroll
        for (int r = 0; r < 4; ++r) {
          int node = base + quad * 4 + r;
          if (node < n) {
            float v = acc[nt][r] + bias_r[nt];
            st_f(out, (size_t)node * COUT + c, v);
            if (BNOUT) { statS[nt] += v; statQ[nt] += v * v; }
          }
        }
      }
    }
  }

  if (BNOUT) {  // COUT==64 whenever BNOUT: every lane owns 4 real channels
#pragma unroll
    for (int nt = 0; nt < NT; ++nt) {
      statS[nt] += __shfl_xor(statS[nt], 16);
      statS[nt] += __shfl_xor(statS[nt], 32);
      statQ[nt] += __shfl_xor(statQ[nt], 16);
      statQ[nt] += __shfl_xor(statQ[nt], 32);
    }
    if (quad == 0) {
#pragma unroll
      for (int nt = 0; nt < NT; ++nt) {
        sRed[0][wave][nt * 16 + col16] = statS[nt];
        sRed[1][wave][nt * 16 + col16] = statQ[nt];
      }
    }
    __syncthreads();
    if (threadIdx.x < 64) {
      int c = threadIdx.x;
      float s = sRed[0][0][c] + sRed[0][1][c] + sRed[0][2][c] + sRed[0][3][c];
      float q = sRed[1][0][c] + sRed[1][1][c] + sRed[1][2][c] + sRed[1][3][c];
      atomicAdd(&statsOut[c], s);
      atomicAdd(&statsOut[64 + c], q);
    }
  }
}

// ------------------------------------------------------------------ launcher
extern "C" void kernel_launch(void* const* d_in, const int* in_sizes, int n_in,
                              void* d_out, int out_size, void* d_ws, size_t ws_size,
                              hipStream_t stream) {
  const float* x = (const float*)d_in[0];
  const void* ei = d_in[1];
  const float* Wl0 = (const float*)d_in[2];
  const float* Wr0 = (const float*)d_in[3];
  const float* b0 = (const float*)d_in[4];
  const float* Wl1 = (const float*)d_in[5];
  const float* Wr1 = (const float*)d_in[6];
  const float* b1 = (const float*)d_in[7];
  const float* Wl2 = (const float*)d_in[8];
  const float* Wr2 = (const float*)d_in[9];
  const float* b2 = (const float*)d_in[10];
  const float* g0 = (const float*)d_in[11];
  const float* be0 = (const float*)d_in[12];
  const float* g1 = (const float*)d_in[13];
  const float* be1 = (const float*)d_in[14];

  const int N = in_sizes[0] / 64;
  const int E = in_sizes[1] / 2;
  const int NB = (N + 511) >> 9;
  const int NBLK = 256;
  const int chunk = (E + NBLK - 1) / NBLK;
  int sh = 0;  // 8 src-chunks cover [0,N): chunk = src >> sh, 8<<sh >= N
  while ((8 << sh) < N) ++sh;

  // ---- d_ws carve: ~8.0 MB ----
  char* w = (char*)d_ws;
  auto carve = [&](size_t bytes) {
    void* p = (void*)w;
    w += (bytes + 255) & ~(size_t)255;
    return p;
  };
  int* dflag = (int*)carve(4);
  float* stats = (float*)carve(1024);  // [L0: sum|sumsq][L1: sum|sumsq]
  int* row_start = (int*)carve((size_t)(N + 1) * 4);
  unsigned* csr = (unsigned*)carve((size_t)E * 4);
  int* hist = (int*)carve((size_t)NBLK * NB * 4);
  int* offs = (int*)carve((size_t)NBLK * NB * 4);
  int* bucket_base = (int*)carve((size_t)(NB + 1) * 4);
  unsigned char* rsc8 = (unsigned char*)carve((size_t)N * 8);
  // runtime fallback: if workspace is too small for rsc8, run unchunked
  size_t used = (size_t)(w - (char*)d_ws);
  unsigned char* rsc8p = (used <= ws_size) ? rsc8 : nullptr;

  float* statsA = stats;
  float* statsB = stats + 128;

  // feature buffers outside d_ws (both bf16, pre-BN):
  unsigned short* B = (unsigned short*)d_out;  // 12.8MB <= 16MB out buffer
  unsigned short* A = (unsigned short*)const_cast<float*>(x);  // x dead after L0

  const int SG = 768;  // 3 blocks/CU resident at 52.7KB LDS

  // ---- CSR build (no global atomics) ----
  k_probe<<<1, 256, 0, stream>>>((const int*)ei, E, dflag);
  k_hist<<<NBLK, 256, 0, stream>>>(ei, E, N, dflag, NB, chunk, hist);
  k_btot<<<1, 256, 0, stream>>>(hist, NBLK, NB, bucket_base, stats);
  k_hoff<<<NB, 64, 0, stream>>>(hist, NBLK, NB, bucket_base, offs);
  k_scat<<<NBLK, 256, 0, stream>>>(ei, E, N, dflag, NB, chunk, offs, csr);
  k_fine<<<NB, 256, 0, stream>>>(csr, bucket_base, N, sh, row_start, rsc8p);

  // ---- layer 0: x (fp32) -> B (bf16 pre-BN in d_out); stats -> statsA ----
  k_sage<64, false, true, float, unsigned short><<<SG, 256, 0, stream>>>(
      x, row_start, (const int*)csr, rsc8p, Wl0, Wr0, b0,
      statsA, g0, be0, statsA, B, N);

  // ---- layer 1: BN0(B) -> A (bf16 pre-BN in x's buffer); stats -> statsB ----
  k_sage<64, true, true, unsigned short, unsigned short><<<SG, 256, 0, stream>>>(
      B, row_start, (const int*)csr, rsc8p, Wl1, Wr1, b1,
      statsA, g0, be0, statsB, A, N);

  // ---- layer 2: BN1(A) -> d_out (fp32, overwrites B scratch) ----
  k_sage<40, true, false, unsigned short, float><<<SG, 256, 0, stream>>>(
      A, row_start, (const int*)csr, rsc8p, Wl2, Wr2, b2,
      statsB, g1, be1, statsB, (float*)d_out, N);
}

// Round 2
// 448.704 us; speedup vs baseline: 3.2000x; 3.2000x over previous
//
#include <hip/hip_runtime.h>

// SAGE_38113539785173 — 3-layer GraphSAGE inference on MI355X (gfx950).
// Round 11: revert round-10 chunking (FAILED: FETCH 185->146MB confirmed the
//   locality mechanism, but per-(node,chunk) ranges of ~2 edges collapsed
//   gather MLP 16->~2 rows in flight -> latency-bound 380GB/s, 3.6x slower).
//   Ladder fact recorded: gather is BYTE-RATE-walled at ~1.75TB/s on the
//   L2-miss/L3 path only while MLP is saturated; reuse ceiling is 2x/XCD
//   (compulsory floor 102MB/layer vs 170 measured) -> blocking max win ~1.5x
//   and it must not touch per-node edge iteration. Axis abandoned.
// Round-11 consolidation (non-gather tail was ~170us of 515):
//   - k_probe dispatch removed: dtype probe folded into k_hist/k_scat as a
//     deterministic uniform 32-sample check (identical across blocks).
//   - hist transposed to [bucket][block]: k_btot single block now sums
//     per-thread-contiguous int4 rows (was stride-NB gather over 200KB);
//     k_hoff lane reads become coalesced.
//   - gather adds a 2-row mid-drain loop: ~47% of nodes (deg<16) previously
//     fell straight to the 1-row cleanup (4 rows/wave in flight); mid loop
//     holds 8/wave for them.
// Everything else identical to round-9 (516us): fused BN (stats epilogue +
// BNIN prologue), MFMA dual matmul, CSR build with no global atomics,
// SG=1024 / 4 blocks/CU.

constexpr float BN_EPS = 1e-5f;

typedef __attribute__((ext_vector_type(8))) short bf16x8;
typedef __attribute__((ext_vector_type(4))) float f32x4;

// ---- bf16 helpers -----------------------------------------------------------
__device__ __forceinline__ float bf2f(unsigned short u) {
  union { unsigned int i; float f; } c;
  c.i = (unsigned int)u << 16;
  return c.f;
}
__device__ __forceinline__ unsigned short f2bf(float v) {
  union { float f; unsigned int i; } c;
  c.f = v;
  unsigned int r = c.i + 0x7fffu + ((c.i >> 16) & 1u);  // round-nearest-even
  return (unsigned short)(r >> 16);
}

__device__ __forceinline__ void st_f(float* p, size_t i, float v) { p[i] = v; }
__device__ __forceinline__ void st_f(unsigned short* p, size_t i, float v) {
  p[i] = f2bf(v);
}

// row loaders: 16 lanes x (16B fp32 | 8B bf16) per 64-channel row
__device__ __forceinline__ float4 ld_row(const float* p, int row, int li) {
  return ((const float4*)p)[(size_t)row * 16 + li];
}
__device__ __forceinline__ float4 ld_row(const unsigned short* p, int row, int li) {
  ushort4 u = ((const ushort4*)p)[(size_t)row * 16 + li];
  float4 f;
  f.x = bf2f(u.x); f.y = bf2f(u.y); f.z = bf2f(u.z); f.w = bf2f(u.w);
  return f;
}

// ---- edge dtype probe: deterministic, identical result in every block ------
// int64 edges (values < N) have zero high words at odd int32 positions;
// int32 edges have random nonzero values there. 32 fixed samples:
// P(miss | int32) ~ (1/N)^32 ~ 0. Uniform loads -> broadcast, ~1us once.
__device__ __forceinline__ int probe_is32(const int* w, int E) {
  const int twoE = 2 * E;
  int f = 0;
#pragma unroll
  for (int j = 0; j < 32; ++j) {
    long long idx = (long long)(2 * j + 1) * twoE / 64;
    int wi = (int)(idx | 1);
    if (wi < twoE && w[wi] != 0) f = 1;
  }
  return f;
}

__device__ __forceinline__ void load_edge(const void* ei, int e, int E, int is32,
                                          int& src, int& dst) {
  if (is32) {
    const int* p = (const int*)ei;
    src = p[e];
    dst = p[E + e];
  } else {
    const long long* p = (const long long*)ei;
    src = (int)p[e];
    dst = (int)p[(long long)E + e];
  }
}

// --------------------------------- CSR phase 1: per-block bucket histograms
// hist layout TRANSPOSED: hist[bucket * NBLK + block]
__global__ __launch_bounds__(256) void k_hist(const void* __restrict__ ei, int E,
                                              int N, int NB, int NBLK, int chunk,
                                              int* __restrict__ hist) {
  __shared__ int h[256];
  h[threadIdx.x] = 0;
  const int is32 = probe_is32((const int*)ei, E);
  __syncthreads();
  int lo = blockIdx.x * chunk;
  int hi = lo + chunk;
  if (hi > E) hi = E;
  for (int e = lo + threadIdx.x; e < hi; e += 256) {
    int src, dst;
    load_edge(ei, e, E, is32, src, dst);
    if ((unsigned)src < (unsigned)N && (unsigned)dst < (unsigned)N)
      atomicAdd(&h[dst >> 9], 1);
  }
  __syncthreads();
  if (threadIdx.x < NB) hist[threadIdx.x * NBLK + blockIdx.x] = h[threadIdx.x];
}

// ------------------- CSR phase 2a: bucket totals + base offsets (+zero stats)
__global__ __launch_bounds__(256) void k_btot(const int* __restrict__ hist,
                                              int NBLK, int NB,
                                              int* __restrict__ bucket_base,
                                              float* __restrict__ stats) {
  stats[threadIdx.x] = 0.0f;  // zero both layers' raw-sum slots (256 floats)
  __shared__ int part[256];
  int t = threadIdx.x;
  int s = 0;
  if (t < NB) {
    const int4* hp = (const int4*)(hist + (size_t)t * NBLK);
    for (int b = 0; b < (NBLK >> 2); ++b) {
      int4 v = hp[b];
      s += v.x + v.y + v.z + v.w;
    }
  }
  part[t] = s;
  __syncthreads();
  for (int off = 1; off < 256; off <<= 1) {
    int u = (t >= off) ? part[t - off] : 0;
    __syncthreads();
    part[t] += u;
    __syncthreads();
  }
  if (t < NB) bucket_base[t] = part[t] - s;
  if (t == NB - 1) bucket_base[NB] = part[t];
}

// --------------------------------- CSR phase 2b: per-(block,bucket) offsets
__global__ __launch_bounds__(64) void k_hoff(const int* __restrict__ hist,
                                             int NBLK, int NB,
                                             const int* __restrict__ bucket_base,
                                             int* __restrict__ offs) {
  int b = blockIdx.x;
  int lane = threadIdx.x;
  int carry = bucket_base[b];
  for (int c = 0; c < NBLK; c += 64) {
    int blk = c + lane;
    int v = (blk < NBLK) ? hist[(size_t)b * NBLK + blk] : 0;  // coalesced
    int incl = v;
    for (int off = 1; off < 64; off <<= 1) {
      int u = __shfl_up(incl, off);
      if (lane >= off) incl += u;
    }
    if (blk < NBLK) offs[blk * NB + b] = carry + incl - v;
    carry += __shfl(incl, 63);
  }
}

// --------------------------------- CSR phase 3: bucket-grouped scatter
__global__ __launch_bounds__(256) void k_scat(const void* __restrict__ ei, int E,
                                              int N, int NB, int chunk,
                                              const int* __restrict__ offs,
                                              unsigned* __restrict__ csr) {
  __shared__ int cur[256];
  if (threadIdx.x < NB) cur[threadIdx.x] = offs[blockIdx.x * NB + threadIdx.x];
  const int is32 = probe_is32((const int*)ei, E);
  __syncthreads();
  int lo = blockIdx.x * chunk;
  int hi = lo + chunk;
  if (hi > E) hi = E;
  for (int e = lo + threadIdx.x; e < hi; e += 256) {
    int src, dst;
    load_edge(ei, e, E, is32, src, dst);
    if ((unsigned)src < (unsigned)N && (unsigned)dst < (unsigned)N) {
      int p = atomicAdd(&cur[dst >> 9], 1);
      csr[p] = ((unsigned)src << 9) | (unsigned)(dst & 511);
    }
  }
}

// --------------------------------- CSR phase 4: per-bucket fine permutation
__global__ __launch_bounds__(256) void k_fine(unsigned* __restrict__ csr,
                                              const int* __restrict__ bucket_base,
                                              int N, int* __restrict__ row_start) {
  constexpr int CAP = 12288;
  __shared__ unsigned lrec[CAP];
  __shared__ int lcnt[512];
  __shared__ int cur[512];
  __shared__ int wtot[4];
  const int b = blockIdx.x;
  const int lo = bucket_base[b];
  int cnt = bucket_base[b + 1] - lo;
  if (cnt > CAP) cnt = CAP;
  const int t = threadIdx.x;
  lcnt[t] = 0;
  lcnt[t + 256] = 0;
  __syncthreads();
  for (int i = t; i < cnt; i += 256) {
    unsigned r = csr[lo + i];
    lrec[i] = r;
    atomicAdd(&lcnt[r & 511], 1);
  }
  __syncthreads();
  int v0 = lcnt[2 * t], v1 = lcnt[2 * t + 1];
  int s = v0 + v1;
  int incl = s;
  const int lane = t & 63;
  for (int off = 1; off < 64; off <<= 1) {
    int u = __shfl_up(incl, off);
    if (lane >= off) incl += u;
  }
  const int wv = t >> 6;
  if (lane == 63) wtot[wv] = incl;
  __syncthreads();
  int woff = 0;
  for (int i = 0; i < wv; ++i) woff += wtot[i];
  int excl = woff + incl - s;
  cur[2 * t] = excl;
  cur[2 * t + 1] = excl + v0;
  int gi = b * 512 + 2 * t;
  if (gi <= N) row_start[gi] = lo + excl;
  if (gi + 1 <= N) row_start[gi + 1] = lo + excl + v0;
  __syncthreads();
  for (int i = t; i < cnt; i += 256) {
    unsigned r = lrec[i];
    int p = atomicAdd(&cur[r & 511], 1);
    csr[lo + p] = r >> 9;
  }
}

// --------------- fused gather-mean + MFMA dual matmul + BN-in + BN-out stats
template <int COUT, bool BNIN, bool BNOUT, typename TI, typename TO>
__global__ __launch_bounds__(256, 4) void k_sage(
    const TI* __restrict__ hin, const int* __restrict__ row_start,
    const int* __restrict__ csr, const float* __restrict__ Wl,
    const float* __restrict__ Wr, const float* __restrict__ bias,
    const float* __restrict__ statsIn, const float* __restrict__ gIn,
    const float* __restrict__ beIn, float* __restrict__ statsOut,
    TO* __restrict__ out, int n) {
  constexpr int NT = (COUT + 15) / 16;
  __shared__ short sWf[NT][4][64][8];  // B-fragments: [nt][kt][lane][j]
  __shared__ short sA[4][16][136];     // [wave][node][k: mean 0..63|self 64..127]
  __shared__ float sBN[2][64];         // BNIN: per-channel scale / shift
  __shared__ float sRed[2][4][64];     // BNOUT: per-wave channel partials

  for (int t = threadIdx.x; t < NT * 4 * 64; t += 256) {
    int lane = t & 63;
    int kt = (t >> 6) & 3;
    int nt = t >> 8;
    int kbase = kt * 32 + (lane >> 4) * 8;
    int col = nt * 16 + (lane & 15);
#pragma unroll
    for (int j = 0; j < 8; ++j) {
      int k = kbase + j;
      float wv = 0.0f;
      if (col < COUT) wv = (k < 64) ? Wl[k * COUT + col] : Wr[(k - 64) * COUT + col];
      sWf[nt][kt][lane][j] = (short)f2bf(wv);
    }
  }
  if (BNIN && threadIdx.x < 64) {
    int c = threadIdx.x;
    float inv = 1.0f / (float)n;
    float mu = statsIn[c] * inv;
    float var = statsIn[64 + c] * inv - mu * mu;
    var = var < 0.f ? 0.f : var;
    float sc = gIn[c] * rsqrtf(var + BN_EPS);
    sBN[0][c] = sc;
    sBN[1][c] = beIn[c] - mu * sc;
  }
  __syncthreads();

  const int wave = threadIdx.x >> 6;
  const int lane = threadIdx.x & 63;
  const int g = lane >> 4;
  const int li = lane & 15;
  const int quad = lane >> 4;
  const int col16 = lane & 15;

  // per-lane BN-in coefficients for channels li*4..li*4+3
  float4 bsc = make_float4(1.f, 1.f, 1.f, 1.f);
  float4 bsh = make_float4(0.f, 0.f, 0.f, 0.f);
  if (BNIN) {
    bsc = *(const float4*)&sBN[0][li * 4];
    bsh = *(const float4*)&sBN[1][li * 4];
  }
  auto xf = [&](float4 v) -> float4 {
    if (!BNIN) return v;
    float4 r;
    r.x = fmaxf(v.x * bsc.x + bsh.x, 0.f);
    r.y = fmaxf(v.y * bsc.y + bsh.y, 0.f);
    r.z = fmaxf(v.z * bsc.z + bsh.z, 0.f);
    r.w = fmaxf(v.w * bsc.w + bsh.w, 0.f);
    return r;
  };

  float bias_r[NT];
#pragma unroll
  for (int nt = 0; nt < NT; ++nt) {
    int c = nt * 16 + col16;
    bias_r[nt] = (c < COUT) ? bias[c] : 0.0f;
  }

  float statS[NT], statQ[NT];
#pragma unroll
  for (int nt = 0; nt < NT; ++nt) { statS[nt] = 0.f; statQ[nt] = 0.f; }

  const int wgl = blockIdx.x * 4 + wave;
  const int nstride = gridDim.x * 64;

  for (int base = wgl * 16; base < n; base += nstride) {
#pragma unroll 1
    for (int nb = 0; nb < 16; ++nb) {
      int node = base + nb;
      if (node >= n) break;
      int rs = row_start[node];
      int re = row_start[node + 1];
      float4 acc = make_float4(0.f, 0.f, 0.f, 0.f);
      int e = rs + g;
      for (; e + 12 < re; e += 16) {  // 4 rows in flight per group, 16/wave
        int r0 = csr[e], r1 = csr[e + 4], r2 = csr[e + 8], r3 = csr[e + 12];
        float4 a = xf(ld_row(hin, r0, li));
        float4 b = xf(ld_row(hin, r1, li));
        float4 c = xf(ld_row(hin, r2, li));
        float4 d = xf(ld_row(hin, r3, li));
        acc.x += (a.x + b.x) + (c.x + d.x);
        acc.y += (a.y + b.y) + (c.y + d.y);
        acc.z += (a.z + b.z) + (c.z + d.z);
        acc.w += (a.w + b.w) + (c.w + d.w);
      }
      for (; e + 4 < re; e += 8) {  // 2-row mid-drain: low-deg nodes keep MLP
        int r0 = csr[e], r1 = csr[e + 4];
        float4 a = xf(ld_row(hin, r0, li));
        float4 b = xf(ld_row(hin, r1, li));
        acc.x += a.x + b.x;
        acc.y += a.y + b.y;
        acc.z += a.z + b.z;
        acc.w += a.w + b.w;
      }
      for (; e < re; e += 4) {
        float4 a = xf(ld_row(hin, csr[e], li));
        acc.x += a.x; acc.y += a.y; acc.z += a.z; acc.w += a.w;
      }
      acc.x += __shfl_xor(acc.x, 16); acc.x += __shfl_xor(acc.x, 32);
      acc.y += __shfl_xor(acc.y, 16); acc.y += __shfl_xor(acc.y, 32);
      acc.z += __shfl_xor(acc.z, 16); acc.z += __shfl_xor(acc.z, 32);
      acc.w += __shfl_xor(acc.w, 16); acc.w += __shfl_xor(acc.w, 32);
      int deg = re - rs;
      float invd = 1.0f / (float)(deg > 0 ? deg : 1);
      float4 self = xf(ld_row(hin, node, li));
      ushort4 mv, sv;
      mv.x = f2bf(acc.x * invd); mv.y = f2bf(acc.y * invd);
      mv.z = f2bf(acc.z * invd); mv.w = f2bf(acc.w * invd);
      sv.x = f2bf(self.x); sv.y = f2bf(self.y);
      sv.z = f2bf(self.z); sv.w = f2bf(self.w);
      *(ushort4*)&sA[wave][nb][li * 4] = mv;
      *(ushort4*)&sA[wave][nb][64 + li * 4] = sv;
    }
    __builtin_amdgcn_wave_barrier();

    f32x4 acc[NT];
#pragma unroll
    for (int nt = 0; nt < NT; ++nt) acc[nt] = (f32x4){0.f, 0.f, 0.f, 0.f};
#pragma unroll
    for (int kt = 0; kt < 4; ++kt) {
      bf16x8 a = *(const bf16x8*)&sA[wave][lane & 15][kt * 32 + (lane >> 4) * 8];
#pragma unroll
      for (int nt = 0; nt < NT; ++nt) {
        bf16x8 b = *(const bf16x8*)&sWf[nt][kt][lane][0];
        acc[nt] = __builtin_amdgcn_mfma_f32_16x16x32_bf16(a, b, acc[nt], 0, 0, 0);
      }
    }
    __builtin_amdgcn_wave_barrier();

#pragma unroll
    for (int nt = 0; nt < NT; ++nt) {
      int c = nt * 16 + col16;
      if (c < COUT) {
#pragma unroll
        for (int r = 0; r < 4; ++r) {
          int node = base + quad * 4 + r;
          if (node < n) {
            float v = acc[nt][r] + bias_r[nt];
            st_f(out, (size_t)node * COUT + c, v);
            if (BNOUT) { statS[nt] += v; statQ[nt] += v * v; }
          }
        }
      }
    }
  }

  if (BNOUT) {  // COUT==64 whenever BNOUT: every lane owns 4 real channels
#pragma unroll
    for (int nt = 0; nt < NT; ++nt) {
      statS[nt] += __shfl_xor(statS[nt], 16);
      statS[nt] += __shfl_xor(statS[nt], 32);
      statQ[nt] += __shfl_xor(statQ[nt], 16);
      statQ[nt] += __shfl_xor(statQ[nt], 32);
    }
    if (quad == 0) {
#pragma unroll
      for (int nt = 0; nt < NT; ++nt) {
        sRed[0][wave][nt * 16 + col16] = statS[nt];
        sRed[1][wave][nt * 16 + col16] = statQ[nt];
      }
    }
    __syncthreads();
    if (threadIdx.x < 64) {
      int c = threadIdx.x;
      float s = sRed[0][0][c] + sRed[0][1][c] + sRed[0][2][c] + sRed[0][3][c];
      float q = sRed[1][0][c] + sRed[1][1][c] + sRed[1][2][c] + sRed[1][3][c];
      atomicAdd(&statsOut[c], s);
      atomicAdd(&statsOut[64 + c], q);
    }
  }
}

// ------------------------------------------------------------------ launcher
extern "C" void kernel_launch(void* const* d_in, const int* in_sizes, int n_in,
                              void* d_out, int out_size, void* d_ws, size_t ws_size,
                              hipStream_t stream) {
  const float* x = (const float*)d_in[0];
  const void* ei = d_in[1];
  const float* Wl0 = (const float*)d_in[2];
  const float* Wr0 = (const float*)d_in[3];
  const float* b0 = (const float*)d_in[4];
  const float* Wl1 = (const float*)d_in[5];
  const float* Wr1 = (const float*)d_in[6];
  const float* b1 = (const float*)d_in[7];
  const float* Wl2 = (const float*)d_in[8];
  const float* Wr2 = (const float*)d_in[9];
  const float* b2 = (const float*)d_in[10];
  const float* g0 = (const float*)d_in[11];
  const float* be0 = (const float*)d_in[12];
  const float* g1 = (const float*)d_in[13];
  const float* be1 = (const float*)d_in[14];

  const int N = in_sizes[0] / 64;
  const int E = in_sizes[1] / 2;
  const int NB = (N + 511) >> 9;
  const int NBLK = 256;
  const int chunk = (E + NBLK - 1) / NBLK;

  // ---- d_ws carve: ~7.2 MB ----
  char* w = (char*)d_ws;
  auto carve = [&](size_t bytes) {
    void* p = (void*)w;
    w += (bytes + 255) & ~(size_t)255;
    return p;
  };
  float* stats = (float*)carve(1024);  // [L0: sum|sumsq][L1: sum|sumsq]
  int* row_start = (int*)carve((size_t)(N + 1) * 4);
  unsigned* csr = (unsigned*)carve((size_t)E * 4);
  int* hist = (int*)carve((size_t)NBLK * NB * 4);  // TRANSPOSED [bucket][block]
  int* offs = (int*)carve((size_t)NBLK * NB * 4);
  int* bucket_base = (int*)carve((size_t)(NB + 1) * 4);

  float* statsA = stats;
  float* statsB = stats + 128;

  // feature buffers outside d_ws (both bf16, pre-BN):
  unsigned short* B = (unsigned short*)d_out;  // 12.8MB <= 16MB out buffer
  unsigned short* A = (unsigned short*)const_cast<float*>(x);  // x dead after L0

  const int SG = 1024;  // exactly 4 blocks/CU resident

  // ---- CSR build (no global atomics, no probe dispatch) ----
  k_hist<<<NBLK, 256, 0, stream>>>(ei, E, N, NB, NBLK, chunk, hist);
  k_btot<<<1, 256, 0, stream>>>(hist, NBLK, NB, bucket_base, stats);
  k_hoff<<<NB, 64, 0, stream>>>(hist, NBLK, NB, bucket_base, offs);
  k_scat<<<NBLK, 256, 0, stream>>>(ei, E, N, NB, chunk, offs, csr);
  k_fine<<<NB, 256, 0, stream>>>(csr, bucket_base, N, row_start);

  // ---- layer 0: x (fp32) -> B (bf16 pre-BN in d_out); stats -> statsA ----
  k_sage<64, false, true, float, unsigned short><<<SG, 256, 0, stream>>>(
      x, row_start, (const int*)csr, Wl0, Wr0, b0,
      statsA, g0, be0, statsA, B, N);

  // ---- layer 1: BN0(B) -> A (bf16 pre-BN in x's buffer); stats -> statsB ----
  k_sage<64, true, true, unsigned short, unsigned short><<<SG, 256, 0, stream>>>(
      B, row_start, (const int*)csr, Wl1, Wr1, b1,
      statsA, g0, be0, statsB, A, N);

  // ---- layer 2: BN1(A) -> d_out (fp32, overwrites B scratch) ----
  k_sage<40, true, false, unsigned short, float><<<SG, 256, 0, stream>>>(
      A, row_start, (const int*)csr, Wl2, Wr2, b2,
      statsB, g1, be1, statsB, (float*)d_out, N);
}

// Round 6
// 379.504 us; speedup vs baseline: 3.7835x; 1.1823x over previous
//
#include <hip/hip_runtime.h>

// SAGE_38113539785173 — 3-layer GraphSAGE inference on MI355X (gfx950).
// Round 15 == Round 12 resubmitted verbatim (rounds 12/13/14 all died in
// GPU acquisition; kernel has never run). Theory unchanged:
// Round 12: node-per-group gather.
//   Round-11 datum: gather rate rose 1.75->1.88 TB/s when in-flight rows
//   increased -> CU-side concurrency-limited, not a hard downstream wall.
//   Old gather: 4 groups cooperate per node -> serial reduce/bookkeeping
//   window (no loads in flight) between every node, ~50% duty cycle.
//   New gather: each 16-lane group owns ONE node (4 nodes/wave, 4 passes):
//     - 16 rows in flight per wave sustained (bookkeeping amortized 4x),
//     - cross-lane shfl reduce eliminated (lane-local channel sums ARE the
//       distributed mean layout sA needs),
//     - cost: exec divergence, trip = max of 4 Poisson(16) degs (~25% issue
//       waste, cheap at VALUBusy 20%).
//   Also NBLK 256->512 (k_hist/k_scat were 1 block/CU on a 12.8MB scan).
// Fused BN (stats epilogue + BNIN prologue), MFMA dual matmul, CSR build
// with no global atomics, SG=1024 / 4 blocks/CU unchanged (round-11, 448us).

constexpr float BN_EPS = 1e-5f;

typedef __attribute__((ext_vector_type(8))) short bf16x8;
typedef __attribute__((ext_vector_type(4))) float f32x4;

// ---- bf16 helpers -----------------------------------------------------------
__device__ __forceinline__ float bf2f(unsigned short u) {
  union { unsigned int i; float f; } c;
  c.i = (unsigned int)u << 16;
  return c.f;
}
__device__ __forceinline__ unsigned short f2bf(float v) {
  union { float f; unsigned int i; } c;
  c.f = v;
  unsigned int r = c.i + 0x7fffu + ((c.i >> 16) & 1u);  // round-nearest-even
  return (unsigned short)(r >> 16);
}

__device__ __forceinline__ void st_f(float* p, size_t i, float v) { p[i] = v; }
__device__ __forceinline__ void st_f(unsigned short* p, size_t i, float v) {
  p[i] = f2bf(v);
}

// row loaders: 16 lanes x (16B fp32 | 8B bf16) per 64-channel row
__device__ __forceinline__ float4 ld_row(const float* p, int row, int li) {
  return ((const float4*)p)[(size_t)row * 16 + li];
}
__device__ __forceinline__ float4 ld_row(const unsigned short* p, int row, int li) {
  ushort4 u = ((const ushort4*)p)[(size_t)row * 16 + li];
  float4 f;
  f.x = bf2f(u.x); f.y = bf2f(u.y); f.z = bf2f(u.z); f.w = bf2f(u.w);
  return f;
}

// ---- edge dtype probe: deterministic, identical result in every block ------
__device__ __forceinline__ int probe_is32(const int* w, int E) {
  const int twoE = 2 * E;
  int f = 0;
#pragma unroll
  for (int j = 0; j < 32; ++j) {
    long long idx = (long long)(2 * j + 1) * twoE / 64;
    int wi = (int)(idx | 1);
    if (wi < twoE && w[wi] != 0) f = 1;
  }
  return f;
}

__device__ __forceinline__ void load_edge(const void* ei, int e, int E, int is32,
                                          int& src, int& dst) {
  if (is32) {
    const int* p = (const int*)ei;
    src = p[e];
    dst = p[E + e];
  } else {
    const long long* p = (const long long*)ei;
    src = (int)p[e];
    dst = (int)p[(long long)E + e];
  }
}

// --------------------------------- CSR phase 1: per-block bucket histograms
// hist layout TRANSPOSED: hist[bucket * NBLK + block]
__global__ __launch_bounds__(256) void k_hist(const void* __restrict__ ei, int E,
                                              int N, int NB, int NBLK, int chunk,
                                              int* __restrict__ hist) {
  __shared__ int h[256];
  h[threadIdx.x] = 0;
  const int is32 = probe_is32((const int*)ei, E);
  __syncthreads();
  int lo = blockIdx.x * chunk;
  int hi = lo + chunk;
  if (hi > E) hi = E;
  for (int e = lo + threadIdx.x; e < hi; e += 256) {
    int src, dst;
    load_edge(ei, e, E, is32, src, dst);
    if ((unsigned)src < (unsigned)N && (unsigned)dst < (unsigned)N)
      atomicAdd(&h[dst >> 9], 1);
  }
  __syncthreads();
  if (threadIdx.x < NB) hist[threadIdx.x * NBLK + blockIdx.x] = h[threadIdx.x];
}

// ------------------- CSR phase 2a: bucket totals + base offsets (+zero stats)
__global__ __launch_bounds__(256) void k_btot(const int* __restrict__ hist,
                                              int NBLK, int NB,
                                              int* __restrict__ bucket_base,
                                              float* __restrict__ stats) {
  stats[threadIdx.x] = 0.0f;  // zero both layers' raw-sum slots (256 floats)
  __shared__ int part[256];
  int t = threadIdx.x;
  int s = 0;
  if (t < NB) {
    const int4* hp = (const int4*)(hist + (size_t)t * NBLK);
    for (int b = 0; b < (NBLK >> 2); ++b) {
      int4 v = hp[b];
      s += v.x + v.y + v.z + v.w;
    }
  }
  part[t] = s;
  __syncthreads();
  for (int off = 1; off < 256; off <<= 1) {
    int u = (t >= off) ? part[t - off] : 0;
    __syncthreads();
    part[t] += u;
    __syncthreads();
  }
  if (t < NB) bucket_base[t] = part[t] - s;
  if (t == NB - 1) bucket_base[NB] = part[t];
}

// --------------------------------- CSR phase 2b: per-(block,bucket) offsets
__global__ __launch_bounds__(64) void k_hoff(const int* __restrict__ hist,
                                             int NBLK, int NB,
                                             const int* __restrict__ bucket_base,
                                             int* __restrict__ offs) {
  int b = blockIdx.x;
  int lane = threadIdx.x;
  int carry = bucket_base[b];
  for (int c = 0; c < NBLK; c += 64) {
    int blk = c + lane;
    int v = (blk < NBLK) ? hist[(size_t)b * NBLK + blk] : 0;  // coalesced
    int incl = v;
    for (int off = 1; off < 64; off <<= 1) {
      int u = __shfl_up(incl, off);
      if (lane >= off) incl += u;
    }
    if (blk < NBLK) offs[blk * NB + b] = carry + incl - v;
    carry += __shfl(incl, 63);
  }
}

// --------------------------------- CSR phase 3: bucket-grouped scatter
__global__ __launch_bounds__(256) void k_scat(const void* __restrict__ ei, int E,
                                              int N, int NB, int chunk,
                                              const int* __restrict__ offs,
                                              unsigned* __restrict__ csr) {
  __shared__ int cur[256];
  if (threadIdx.x < NB) cur[threadIdx.x] = offs[blockIdx.x * NB + threadIdx.x];
  const int is32 = probe_is32((const int*)ei, E);
  __syncthreads();
  int lo = blockIdx.x * chunk;
  int hi = lo + chunk;
  if (hi > E) hi = E;
  for (int e = lo + threadIdx.x; e < hi; e += 256) {
    int src, dst;
    load_edge(ei, e, E, is32, src, dst);
    if ((unsigned)src < (unsigned)N && (unsigned)dst < (unsigned)N) {
      int p = atomicAdd(&cur[dst >> 9], 1);
      csr[p] = ((unsigned)src << 9) | (unsigned)(dst & 511);
    }
  }
}

// --------------------------------- CSR phase 4: per-bucket fine permutation
__global__ __launch_bounds__(256) void k_fine(unsigned* __restrict__ csr,
                                              const int* __restrict__ bucket_base,
                                              int N, int* __restrict__ row_start) {
  constexpr int CAP = 12288;
  __shared__ unsigned lrec[CAP];
  __shared__ int lcnt[512];
  __shared__ int cur[512];
  __shared__ int wtot[4];
  const int b = blockIdx.x;
  const int lo = bucket_base[b];
  int cnt = bucket_base[b + 1] - lo;
  if (cnt > CAP) cnt = CAP;
  const int t = threadIdx.x;
  lcnt[t] = 0;
  lcnt[t + 256] = 0;
  __syncthreads();
  for (int i = t; i < cnt; i += 256) {
    unsigned r = csr[lo + i];
    lrec[i] = r;
    atomicAdd(&lcnt[r & 511], 1);
  }
  __syncthreads();
  int v0 = lcnt[2 * t], v1 = lcnt[2 * t + 1];
  int s = v0 + v1;
  int incl = s;
  const int lane = t & 63;
  for (int off = 1; off < 64; off <<= 1) {
    int u = __shfl_up(incl, off);
    if (lane >= off) incl += u;
  }
  const int wv = t >> 6;
  if (lane == 63) wtot[wv] = incl;
  __syncthreads();
  int woff = 0;
  for (int i = 0; i < wv; ++i) woff += wtot[i];
  int excl = woff + incl - s;
  cur[2 * t] = excl;
  cur[2 * t + 1] = excl + v0;
  int gi = b * 512 + 2 * t;
  if (gi <= N) row_start[gi] = lo + excl;
  if (gi + 1 <= N) row_start[gi + 1] = lo + excl + v0;
  __syncthreads();
  for (int i = t; i < cnt; i += 256) {
    unsigned r = lrec[i];
    int p = atomicAdd(&cur[r & 511], 1);
    csr[lo + p] = r >> 9;
  }
}

// --------------- fused gather-mean + MFMA dual matmul + BN-in + BN-out stats
// Gather: each 16-lane group owns one node (4 nodes/wave/pass, 4 passes).
// Lane-local channel accumulation -> no cross-lane reduce; 16 rows in
// flight per wave sustained.
template <int COUT, bool BNIN, bool BNOUT, typename TI, typename TO>
__global__ __launch_bounds__(256, 4) void k_sage(
    const TI* __restrict__ hin, const int* __restrict__ row_start,
    const int* __restrict__ csr, const float* __restrict__ Wl,
    const float* __restrict__ Wr, const float* __restrict__ bias,
    const float* __restrict__ statsIn, const float* __restrict__ gIn,
    const float* __restrict__ beIn, float* __restrict__ statsOut,
    TO* __restrict__ out, int n) {
  constexpr int NT = (COUT + 15) / 16;
  __shared__ short sWf[NT][4][64][8];  // B-fragments: [nt][kt][lane][j]
  __shared__ short sA[4][16][136];     // [wave][node][k: mean 0..63|self 64..127]
  __shared__ float sBN[2][64];         // BNIN: per-channel scale / shift
  __shared__ float sRed[2][4][64];     // BNOUT: per-wave channel partials

  for (int t = threadIdx.x; t < NT * 4 * 64; t += 256) {
    int lane = t & 63;
    int kt = (t >> 6) & 3;
    int nt = t >> 8;
    int kbase = kt * 32 + (lane >> 4) * 8;
    int col = nt * 16 + (lane & 15);
#pragma unroll
    for (int j = 0; j < 8; ++j) {
      int k = kbase + j;
      float wv = 0.0f;
      if (col < COUT) wv = (k < 64) ? Wl[k * COUT + col] : Wr[(k - 64) * COUT + col];
      sWf[nt][kt][lane][j] = (short)f2bf(wv);
    }
  }
  if (BNIN && threadIdx.x < 64) {
    int c = threadIdx.x;
    float inv = 1.0f / (float)n;
    float mu = statsIn[c] * inv;
    float var = statsIn[64 + c] * inv - mu * mu;
    var = var < 0.f ? 0.f : var;
    float sc = gIn[c] * rsqrtf(var + BN_EPS);
    sBN[0][c] = sc;
    sBN[1][c] = beIn[c] - mu * sc;
  }
  __syncthreads();

  const int wave = threadIdx.x >> 6;
  const int lane = threadIdx.x & 63;
  const int g = lane >> 4;
  const int li = lane & 15;
  const int quad = lane >> 4;
  const int col16 = lane & 15;

  // per-lane BN-in coefficients for channels li*4..li*4+3
  float4 bsc = make_float4(1.f, 1.f, 1.f, 1.f);
  float4 bsh = make_float4(0.f, 0.f, 0.f, 0.f);
  if (BNIN) {
    bsc = *(const float4*)&sBN[0][li * 4];
    bsh = *(const float4*)&sBN[1][li * 4];
  }
  auto xf = [&](float4 v) -> float4 {
    if (!BNIN) return v;
    float4 r;
    r.x = fmaxf(v.x * bsc.x + bsh.x, 0.f);
    r.y = fmaxf(v.y * bsc.y + bsh.y, 0.f);
    r.z = fmaxf(v.z * bsc.z + bsh.z, 0.f);
    r.w = fmaxf(v.w * bsc.w + bsh.w, 0.f);
    return r;
  };

  float bias_r[NT];
#pragma unroll
  for (int nt = 0; nt < NT; ++nt) {
    int c = nt * 16 + col16;
    bias_r[nt] = (c < COUT) ? bias[c] : 0.0f;
  }

  float statS[NT], statQ[NT];
#pragma unroll
  for (int nt = 0; nt < NT; ++nt) { statS[nt] = 0.f; statQ[nt] = 0.f; }

  const int wgl = blockIdx.x * 4 + wave;
  const int nstride = gridDim.x * 64;

  for (int base = wgl * 16; base < n; base += nstride) {
    // gather: group g owns node base + pass*4 + g; lane-local channel sums
#pragma unroll 1
    for (int pass = 0; pass < 4; ++pass) {
      const int nb = pass * 4 + g;
      const int node = base + nb;
      const bool valid = node < n;
      int rs = valid ? row_start[node] : 0;
      int re = valid ? row_start[node + 1] : 0;
      float4 acc = make_float4(0.f, 0.f, 0.f, 0.f);
      int e = rs;
      for (; e + 3 < re; e += 4) {  // 4 rows in flight per group
        int r0 = csr[e], r1 = csr[e + 1], r2 = csr[e + 2], r3 = csr[e + 3];
        float4 a = xf(ld_row(hin, r0, li));
        float4 b = xf(ld_row(hin, r1, li));
        float4 c = xf(ld_row(hin, r2, li));
        float4 d = xf(ld_row(hin, r3, li));
        acc.x += (a.x + b.x) + (c.x + d.x);
        acc.y += (a.y + b.y) + (c.y + d.y);
        acc.z += (a.z + b.z) + (c.z + d.z);
        acc.w += (a.w + b.w) + (c.w + d.w);
      }
      for (; e + 1 < re; e += 2) {
        int r0 = csr[e], r1 = csr[e + 1];
        float4 a = xf(ld_row(hin, r0, li));
        float4 b = xf(ld_row(hin, r1, li));
        acc.x += a.x + b.x;
        acc.y += a.y + b.y;
        acc.z += a.z + b.z;
        acc.w += a.w + b.w;
      }
      for (; e < re; ++e) {
        float4 a = xf(ld_row(hin, csr[e], li));
        acc.x += a.x; acc.y += a.y; acc.z += a.z; acc.w += a.w;
      }
      if (valid) {
        int deg = re - rs;
        float invd = 1.0f / (float)(deg > 0 ? deg : 1);
        float4 self = xf(ld_row(hin, node, li));
        ushort4 mv, sv;
        mv.x = f2bf(acc.x * invd); mv.y = f2bf(acc.y * invd);
        mv.z = f2bf(acc.z * invd); mv.w = f2bf(acc.w * invd);
        sv.x = f2bf(self.x); sv.y = f2bf(self.y);
        sv.z = f2bf(self.z); sv.w = f2bf(self.w);
        *(ushort4*)&sA[wave][nb][li * 4] = mv;
        *(ushort4*)&sA[wave][nb][64 + li * 4] = sv;
      }
    }
    __builtin_amdgcn_wave_barrier();

    f32x4 acc[NT];
#pragma unroll
    for (int nt = 0; nt < NT; ++nt) acc[nt] = (f32x4){0.f, 0.f, 0.f, 0.f};
#pragma unroll
    for (int kt = 0; kt < 4; ++kt) {
      bf16x8 a = *(const bf16x8*)&sA[wave][lane & 15][kt * 32 + (lane >> 4) * 8];
#pragma unroll
      for (int nt = 0; nt < NT; ++nt) {
        bf16x8 b = *(const bf16x8*)&sWf[nt][kt][lane][0];
        acc[nt] = __builtin_amdgcn_mfma_f32_16x16x32_bf16(a, b, acc[nt], 0, 0, 0);
      }
    }
    __builtin_amdgcn_wave_barrier();

#pragma unroll
    for (int nt = 0; nt < NT; ++nt) {
      int c = nt * 16 + col16;
      if (c < COUT) {
#pragma unroll
        for (int r = 0; r < 4; ++r) {
          int node = base + quad * 4 + r;
          if (node < n) {
            float v = acc[nt][r] + bias_r[nt];
            st_f(out, (size_t)node * COUT + c, v);
            if (BNOUT) { statS[nt] += v; statQ[nt] += v * v; }
          }
        }
      }
    }
  }

  if (BNOUT) {  // COUT==64 whenever BNOUT: every lane owns 4 real channels
#pragma unroll
    for (int nt = 0; nt < NT; ++nt) {
      statS[nt] += __shfl_xor(statS[nt], 16);
      statS[nt] += __shfl_xor(statS[nt], 32);
      statQ[nt] += __shfl_xor(statQ[nt], 16);
      statQ[nt] += __shfl_xor(statQ[nt], 32);
    }
    if (quad == 0) {
#pragma unroll
      for (int nt = 0; nt < NT; ++nt) {
        sRed[0][wave][nt * 16 + col16] = statS[nt];
        sRed[1][wave][nt * 16 + col16] = statQ[nt];
      }
    }
    __syncthreads();
    if (threadIdx.x < 64) {
      int c = threadIdx.x;
      float s = sRed[0][0][c] + sRed[0][1][c] + sRed[0][2][c] + sRed[0][3][c];
      float q = sRed[1][0][c] + sRed[1][1][c] + sRed[1][2][c] + sRed[1][3][c];
      atomicAdd(&statsOut[c], s);
      atomicAdd(&statsOut[64 + c], q);
    }
  }
}

// ------------------------------------------------------------------ launcher
extern "C" void kernel_launch(void* const* d_in, const int* in_sizes, int n_in,
                              void* d_out, int out_size, void* d_ws, size_t ws_size,
                              hipStream_t stream) {
  const float* x = (const float*)d_in[0];
  const void* ei = d_in[1];
  const float* Wl0 = (const float*)d_in[2];
  const float* Wr0 = (const float*)d_in[3];
  const float* b0 = (const float*)d_in[4];
  const float* Wl1 = (const float*)d_in[5];
  const float* Wr1 = (const float*)d_in[6];
  const float* b1 = (const float*)d_in[7];
  const float* Wl2 = (const float*)d_in[8];
  const float* Wr2 = (const float*)d_in[9];
  const float* b2 = (const float*)d_in[10];
  const float* g0 = (const float*)d_in[11];
  const float* be0 = (const float*)d_in[12];
  const float* g1 = (const float*)d_in[13];
  const float* be1 = (const float*)d_in[14];

  const int N = in_sizes[0] / 64;
  const int E = in_sizes[1] / 2;
  const int NB = (N + 511) >> 9;
  const int NBLK = 512;  // 2 blocks/CU for the edge scans
  const int chunk = (E + NBLK - 1) / NBLK;

  // ---- d_ws carve: ~7.6 MB ----
  char* w = (char*)d_ws;
  auto carve = [&](size_t bytes) {
    void* p = (void*)w;
    w += (bytes + 255) & ~(size_t)255;
    return p;
  };
  float* stats = (float*)carve(1024);  // [L0: sum|sumsq][L1: sum|sumsq]
  int* row_start = (int*)carve((size_t)(N + 1) * 4);
  unsigned* csr = (unsigned*)carve((size_t)E * 4);
  int* hist = (int*)carve((size_t)NBLK * NB * 4);  // TRANSPOSED [bucket][block]
  int* offs = (int*)carve((size_t)NBLK * NB * 4);
  int* bucket_base = (int*)carve((size_t)(NB + 1) * 4);

  float* statsA = stats;
  float* statsB = stats + 128;

  // feature buffers outside d_ws (both bf16, pre-BN):
  unsigned short* B = (unsigned short*)d_out;  // 12.8MB <= 16MB out buffer
  unsigned short* A = (unsigned short*)const_cast<float*>(x);  // x dead after L0

  const int SG = 1024;  // exactly 4 blocks/CU resident

  // ---- CSR build (no global atomics, no probe dispatch) ----
  k_hist<<<NBLK, 256, 0, stream>>>(ei, E, N, NB, NBLK, chunk, hist);
  k_btot<<<1, 256, 0, stream>>>(hist, NBLK, NB, bucket_base, stats);
  k_hoff<<<NB, 64, 0, stream>>>(hist, NBLK, NB, bucket_base, offs);
  k_scat<<<NBLK, 256, 0, stream>>>(ei, E, N, NB, chunk, offs, csr);
  k_fine<<<NB, 256, 0, stream>>>(csr, bucket_base, N, row_start);

  // ---- layer 0: x (fp32) -> B (bf16 pre-BN in d_out); stats -> statsA ----
  k_sage<64, false, true, float, unsigned short><<<SG, 256, 0, stream>>>(
      x, row_start, (const int*)csr, Wl0, Wr0, b0,
      statsA, g0, be0, statsA, B, N);

  // ---- layer 1: BN0(B) -> A (bf16 pre-BN in x's buffer); stats -> statsB ----
  k_sage<64, true, true, unsigned short, unsigned short><<<SG, 256, 0, stream>>>(
      B, row_start, (const int*)csr, Wl1, Wr1, b1,
      statsA, g0, be0, statsB, A, N);

  // ---- layer 2: BN1(A) -> d_out (fp32, overwrites B scratch) ----
  k_sage<40, true, false, unsigned short, float><<<SG, 256, 0, stream>>>(
      A, row_start, (const int*)csr, Wl2, Wr2, b2,
      statsB, g1, be1, statsB, (float*)d_out, N);
}